// Round 10
// baseline (127.929 us; speedup 1.0000x reference)
//
#include <hip/hip_runtime.h>

// Problem: B=8, T_en=T_de=D=U=256.
// out = de + softmax_e( sum_u tanh(ae[b,e,u]+ad[b,t,u]) * nu[u] ) @ en
// tanh(x) = 1 - 2/(e^{2x}+1);  e^{2x} = Ea * sd with
//   Ea[b,e,u] = exp2(C*ae), sd[b,t,u] = exp2(C*ad), C = 2*log2(e)
//   (precomputed in gemm epilogue -> attn hot loop: no transcendentals
//    except 1 rcp per 4 u).
// Softmax: mu = SUM(nu) - 2*acc, acc = sum_u nu/(E+1); SUM(nu) drops out
//   -> alpha = exp2((min_acc - acc)*C) / sum.
// 4-way rcp combine: sum nu_i/A_i = (n01*p23 + n23*p01)/(p01*p23).
// Harness note: ~80us/iter is fixed overhead (256MB d_ws 0xAA poison = 40us
// fill + restores); only gemm+attn (~32us) is compressible.

#define C2LOG2E 2.8853900817779268f   // 2*log2(e)

__device__ __forceinline__ const float* uptr(const float* p) {
    unsigned long long v = (unsigned long long)p;
    unsigned lo = __builtin_amdgcn_readfirstlane((unsigned)v);
    unsigned hi = __builtin_amdgcn_readfirstlane((unsigned)(v >> 32));
    return (const float*)((((unsigned long long)hi) << 32) | lo);
}

// ---------------------------------------------------------------------------
// Projection GEMMs + exp2 epilogue. grid 512 x 256thr:
//   blk<256 : Ea packed  att_enT4[b][u>>2][e][u&3] = exp2(C*(en@w_en))
//   blk>=256: sd         att_de_exp[b][t][u]       = exp2(C*(de@w_de))
// Block = 8 rows x 256 cols; wave wv = k-quarter for ALL 8 rows (A via 8
// uniform s_load ptrs; w coalesced b128, 4-deep prefetch). Partials (4 waves
// x 8 rows x 256) reduced through 32KB LDS. w traffic 256KB/block -> 128MB.
// ---------------------------------------------------------------------------
__global__ __launch_bounds__(256, 2) void gemm2(
    const float* __restrict__ en, const float* __restrict__ de,
    const float* __restrict__ w_en, const float* __restrict__ w_de,
    float* __restrict__ att_enT4, float* __restrict__ att_de_exp)
{
    __shared__ float part[4 * 8 * 256];   // 32KB [wave][row][col]; reused

    const int isDe = blockIdx.x >> 8;
    const int rb   = blockIdx.x & 255;
    const float* x = isDe ? de : en;
    const float* w = isDe ? w_de : w_en;

    const int tid  = threadIdx.x;
    const int lane = tid & 63;
    const int wv   = __builtin_amdgcn_readfirstlane(tid >> 6);
    const int r0   = rb * 8;
    const int c0   = lane << 2;
    const int k0   = wv << 6;

    const float* ar[8];
    #pragma unroll
    for (int j = 0; j < 8; ++j)
        ar[j] = uptr(x + (r0 + j) * 256 + k0);
    const float* wk = w + k0 * 256 + c0;

    float4 acc[8];
    #pragma unroll
    for (int j = 0; j < 8; ++j) acc[j] = float4{0, 0, 0, 0};

    float4 wb[4], wn[4];
    #pragma unroll
    for (int j = 0; j < 4; ++j)
        wb[j] = *(const float4*)(wk + j * 256);

    for (int kk = 0; kk < 64; kk += 4) {
        if (kk < 60) {
            #pragma unroll
            for (int j = 0; j < 4; ++j)
                wn[j] = *(const float4*)(wk + (kk + 4 + j) * 256);
        }
        #pragma unroll
        for (int j = 0; j < 4; ++j) {
            const int k = kk + j;
            #pragma unroll
            for (int r = 0; r < 8; ++r) {
                const float a = ar[r][k];          // s_load
                acc[r].x = fmaf(a, wb[j].x, acc[r].x);
                acc[r].y = fmaf(a, wb[j].y, acc[r].y);
                acc[r].z = fmaf(a, wb[j].z, acc[r].z);
                acc[r].w = fmaf(a, wb[j].w, acc[r].w);
            }
        }
        #pragma unroll
        for (int j = 0; j < 4; ++j) wb[j] = wn[j];
    }

    #pragma unroll
    for (int r = 0; r < 8; ++r)
        *(float4*)&part[(wv * 8 + r) * 256 + c0] = acc[r];
    __syncthreads();

    // reduce 4 k-partials; thread t = column u; scale + exp2
    const int t = tid;
    float s[8];
    #pragma unroll
    for (int j = 0; j < 8; ++j) {
        const float v = part[(0 * 8 + j) * 256 + t] + part[(1 * 8 + j) * 256 + t]
                      + part[(2 * 8 + j) * 256 + t] + part[(3 * 8 + j) * 256 + t];
        s[j] = __builtin_amdgcn_exp2f(v * C2LOG2E);
    }

    if (isDe) {
        const int rr0 = rb * 8;
        #pragma unroll
        for (int j = 0; j < 8; ++j)
            att_de_exp[(rr0 + j) * 256 + t] = s[j];
    } else {
        const int b  = rb >> 5;
        const int er = (rb & 31) * 8;
        __syncthreads();                   // all partial reads done
        #pragma unroll
        for (int j = 0; j < 8; ++j)
            part[j * 256 + t] = s[j];      // [e_local][u]
        __syncthreads();
        // pack: att_enT4[b][ug][e][u&3]; thread t -> ug=t&63, e_local=t>>6,+4
        const int ug = t & 63;
        const int s0 = t >> 6;             // 0..3
        #pragma unroll
        for (int q = 0; q < 2; ++q) {
            const int el = s0 + q * 4;
            const float4 v = *(const float4*)&part[el * 256 + (ug << 2)];
            *(float4*)(att_enT4 + b * 65536 + ug * 1024 + (er + el) * 4) = v;
        }
    }
}

// ---------------------------------------------------------------------------
// Attention. grid 1024 x 256thr, TT=2, b = blk&7 (XCD-affine).
// Stage 1: lane = e; packed b128 Ea loads, 8-deep prefetch ring (~600cyc of
//   compute per boundary covers L2 latency); sd/nu uniform s_loads; E=Ea*sd;
//   4-way rcp combine -> no exp2 in hot loop.
// Stage 2: waves 0,1 softmax (min-trick). Stage 3: thread=d, alphas uniform
//   b128 broadcasts, en coalesced, 8-deep preload.
// ---------------------------------------------------------------------------
__global__ __launch_bounds__(256, 4) void attn_kernel(
    const float* __restrict__ att_enT4,   // (B,64,T_en,4): Ea packed
    const float* __restrict__ att_de_exp, // (B,T_de,U): sd
    const float* __restrict__ en_seq,     // (B,T_en,D)
    const float* __restrict__ de_seq,     // (B,T_de,D)
    const float* __restrict__ nu,         // (U)
    float* __restrict__ out)              // (B,T_de,D)
{
    const int blk  = blockIdx.x;          // 0..1023
    const int b    = blk & 7;
    const int t0   = (blk >> 3) << 1;
    const int tid  = threadIdx.x;
    const int lane = tid & 63;
    const int wv   = __builtin_amdgcn_readfirstlane(tid >> 6);

    __shared__ float s_mu[2][256];
    __shared__ float s_al[2][256];

    const float* aw  = att_enT4 + b * 65536 + (((wv << 6) + lane) << 2);
    const float* sd0 = uptr(att_de_exp + (b * 256 + t0) * 256);
    const float* sd1 = uptr(att_de_exp + (b * 256 + t0) * 256 + 256);
    const float* nuu = uptr(nu);

    // ---- Stage 1: acc[t] = sum_u nu[u] / (Ea*sd + 1) ----
    float acc0 = 0.f, acc1 = 0.f;
    float4 cur[8];
    #pragma unroll
    for (int j = 0; j < 8; ++j)
        cur[j] = *(const float4*)(aw + j * 1024);

    for (int ugb = 0; ugb < 64; ugb += 8) {
        float4 nxt[8];
        if (ugb < 56) {
            #pragma unroll
            for (int j = 0; j < 8; ++j)
                nxt[j] = *(const float4*)(aw + (ugb + 8 + j) * 1024);
        }
        #pragma unroll
        for (int j = 0; j < 8; ++j) {
            const int ub = (ugb + j) << 2;
            const float n0 = nuu[ub + 0], n1 = nuu[ub + 1];
            const float n2 = nuu[ub + 2], n3 = nuu[ub + 3];
            const float4 Ea = cur[j];
            {   // t = t0
                const float A0 = fmaf(Ea.x, sd0[ub + 0], 1.f);
                const float A1 = fmaf(Ea.y, sd0[ub + 1], 1.f);
                const float A2 = fmaf(Ea.z, sd0[ub + 2], 1.f);
                const float A3 = fmaf(Ea.w, sd0[ub + 3], 1.f);
                const float p01 = A0 * A1, p23 = A2 * A3;
                const float n01 = fmaf(n0, A1, n1 * A0);
                const float n23 = fmaf(n2, A3, n3 * A2);
                const float num = fmaf(n01, p23, n23 * p01);
                acc0 = fmaf(num, __builtin_amdgcn_rcpf(p01 * p23), acc0);
            }
            {   // t = t0+1
                const float A0 = fmaf(Ea.x, sd1[ub + 0], 1.f);
                const float A1 = fmaf(Ea.y, sd1[ub + 1], 1.f);
                const float A2 = fmaf(Ea.z, sd1[ub + 2], 1.f);
                const float A3 = fmaf(Ea.w, sd1[ub + 3], 1.f);
                const float p01 = A0 * A1, p23 = A2 * A3;
                const float n01 = fmaf(n0, A1, n1 * A0);
                const float n23 = fmaf(n2, A3, n3 * A2);
                const float num = fmaf(n01, p23, n23 * p01);
                acc1 = fmaf(num, __builtin_amdgcn_rcpf(p01 * p23), acc1);
            }
        }
        #pragma unroll
        for (int j = 0; j < 8; ++j) cur[j] = nxt[j];
    }
    const int eidx = (wv << 6) + lane;
    s_mu[0][eidx] = acc0;
    s_mu[1][eidx] = acc1;
    __syncthreads();

    // ---- Stage 2: softmax for t = wv (logits = const - 2*acc) ----
    if (wv < 2) {
        const float4 a = *(const float4*)&s_mu[wv][lane << 2];
        float mn = fminf(fminf(a.x, a.y), fminf(a.z, a.w));
        #pragma unroll
        for (int off = 32; off > 0; off >>= 1)
            mn = fminf(mn, __shfl_xor(mn, off, 64));
        const float p0 = __builtin_amdgcn_exp2f((mn - a.x) * C2LOG2E);
        const float p1 = __builtin_amdgcn_exp2f((mn - a.y) * C2LOG2E);
        const float p2 = __builtin_amdgcn_exp2f((mn - a.z) * C2LOG2E);
        const float p3 = __builtin_amdgcn_exp2f((mn - a.w) * C2LOG2E);
        float ssum = (p0 + p1) + (p2 + p3);
        #pragma unroll
        for (int off = 32; off > 0; off >>= 1)
            ssum += __shfl_xor(ssum, off, 64);
        const float inv = __builtin_amdgcn_rcpf(ssum);
        float4 al; al.x = p0 * inv; al.y = p1 * inv;
        al.z = p2 * inv; al.w = p3 * inv;
        *(float4*)&s_al[wv][lane << 2] = al;
    }
    __syncthreads();

    // ---- Stage 3: out[t][d] = de[t][d] + sum_e alpha[t][e]*en[e][d] ----
    const float* en_b = en_seq + b * 65536 + tid;
    float o0 = 0.f, o1 = 0.f;
    for (int e0 = 0; e0 < 256; e0 += 8) {
        float v[8];
        #pragma unroll
        for (int j = 0; j < 8; ++j) v[j] = en_b[(e0 + j) << 8];
        #pragma unroll
        for (int q = 0; q < 2; ++q) {
            const int eb = e0 + q * 4;
            const float4 A0 = *(const float4*)&s_al[0][eb];  // uniform bcast
            const float4 A1 = *(const float4*)&s_al[1][eb];
            o0 = fmaf(A0.x, v[q*4+0], o0); o1 = fmaf(A1.x, v[q*4+0], o1);
            o0 = fmaf(A0.y, v[q*4+1], o0); o1 = fmaf(A1.y, v[q*4+1], o1);
            o0 = fmaf(A0.z, v[q*4+2], o0); o1 = fmaf(A1.z, v[q*4+2], o1);
            o0 = fmaf(A0.w, v[q*4+3], o0); o1 = fmaf(A1.w, v[q*4+3], o1);
        }
    }
    const int base = (b * 256 + t0) * 256 + tid;
    out[base]       = de_seq[base]       + o0;
    out[base + 256] = de_seq[base + 256] + o1;
}

extern "C" void kernel_launch(void* const* d_in, const int* in_sizes, int n_in,
                              void* d_out, int out_size, void* d_ws, size_t ws_size,
                              hipStream_t stream) {
    const float* en_seq = (const float*)d_in[0];
    const float* de_seq = (const float*)d_in[1];
    const float* w_en   = (const float*)d_in[2];
    const float* w_de   = (const float*)d_in[3];
    const float* nu     = (const float*)d_in[4];
    float* out = (float*)d_out;

    float* att_enT4   = (float*)d_ws;                // 2MB: Ea, packed
    float* att_de_exp = att_enT4 + 8 * 256 * 256;    // 2MB: sd

    gemm2<<<512, 256, 0, stream>>>(en_seq, de_seq, w_en, w_de,
                                   att_enT4, att_de_exp);
    attn_kernel<<<1024, 256, 0, stream>>>(att_enT4, att_de_exp, en_seq,
                                          de_seq, nu, out);
}

// Round 11
// 112.138 us; speedup vs baseline: 1.1408x; 1.1408x over previous
//
#include <hip/hip_runtime.h>

// Problem: B=8, T_en=T_de=D=U=256.
// out = de + softmax_e( sum_u tanh(ae[b,e,u]+ad[b,t,u]) * nu[u] ) @ en
// tanh(x) = 1 - 2/(e^{2x}+1);  e^{2x} = Ea * sd with
//   Ea[b,e,u] = exp2(C*ae), sd[b,t,u] = exp2(C*ad), C = 2*log2(e)  (both
//   precomputed in the gemm epilogue -> attn hot loop has NO transcendentals
//   except 1 rcp per 4 u).
// Softmax identity: mu = SUM(nu) - 2*acc, acc = sum_u nu/(E+1); SUM(nu)
// drops out -> alpha = exp2((min_acc - acc)*C) / sum.
// 4-way rcp combine: sum nu_i/A_i = (n01*p23 + n23*p01) / (p01*p23).
// NOTE (R10 post-mortem): do NOT deepen the Ea ring past 4 — cur[8]/nxt[8]
// spilled to scratch (45MB WRITE_SIZE, 2x attn time). 4-deep is the sweet spot.
// Harness note: ~80us/iter is fixed overhead (256MB d_ws poison = 40us fill
// + restores); kernel-compressible budget is only ~32us.

#define C2LOG2E 2.8853900817779268f   // 2*log2(e)

// Force a wave-uniform pointer value -> compiler can use scalar (s_load) path.
__device__ __forceinline__ const float* uptr(const float* p) {
    unsigned long long v = (unsigned long long)p;
    unsigned lo = __builtin_amdgcn_readfirstlane((unsigned)v);
    unsigned hi = __builtin_amdgcn_readfirstlane((unsigned)(v >> 32));
    return (const float*)((((unsigned long long)hi) << 32) | lo);
}

// ---------------------------------------------------------------------------
// Projection GEMMs + exp2 epilogue. grid 1024 x 256thr:
//   blk<512 : Ea packed  att_enT4[b][u>>2][e][u&3] = exp2(C * (en@w_en))
//   blk>=512: sd         att_de_exp[b][t][u]       = exp2(C * (de@w_de))
// Block = 4 rows x 256 cols. Wave wv = k-quarter [64wv,64wv+64) for ALL 4
// rows (A via uniform s_load ptrs, w as coalesced b128, 4-deep prefetch);
// partials reduced through LDS.
// ---------------------------------------------------------------------------
__global__ __launch_bounds__(256, 4) void gemm2(
    const float* __restrict__ en, const float* __restrict__ de,
    const float* __restrict__ w_en, const float* __restrict__ w_de,
    float* __restrict__ att_enT4, float* __restrict__ att_de_exp)
{
    __shared__ float part[4 * 4 * 256];   // 16KB [wave][row][col]; reused

    const int isDe = blockIdx.x >> 9;
    const int rb   = blockIdx.x & 511;
    const float* x = isDe ? de : en;
    const float* w = isDe ? w_de : w_en;

    const int tid  = threadIdx.x;
    const int lane = tid & 63;
    const int wv   = __builtin_amdgcn_readfirstlane(tid >> 6);
    const int r0   = rb * 4;
    const int c0   = lane << 2;
    const int k0   = wv << 6;

    const float* ar0 = uptr(x + (r0 + 0) * 256 + k0);
    const float* ar1 = uptr(x + (r0 + 1) * 256 + k0);
    const float* ar2 = uptr(x + (r0 + 2) * 256 + k0);
    const float* ar3 = uptr(x + (r0 + 3) * 256 + k0);
    const float* wk  = w + k0 * 256 + c0;

    float4 acc0{0,0,0,0}, acc1{0,0,0,0}, acc2{0,0,0,0}, acc3{0,0,0,0};

    float4 wb[4], wn[4];
    #pragma unroll
    for (int j = 0; j < 4; ++j)
        wb[j] = *(const float4*)(wk + j * 256);

    for (int kk = 0; kk < 64; kk += 4) {
        if (kk < 60) {
            #pragma unroll
            for (int j = 0; j < 4; ++j)
                wn[j] = *(const float4*)(wk + (kk + 4 + j) * 256);
        }
        #pragma unroll
        for (int j = 0; j < 4; ++j) {
            const int k = kk + j;
            const float a0 = ar0[k], a1 = ar1[k];   // s_load
            const float a2 = ar2[k], a3 = ar3[k];
            acc0.x = fmaf(a0, wb[j].x, acc0.x); acc0.y = fmaf(a0, wb[j].y, acc0.y);
            acc0.z = fmaf(a0, wb[j].z, acc0.z); acc0.w = fmaf(a0, wb[j].w, acc0.w);
            acc1.x = fmaf(a1, wb[j].x, acc1.x); acc1.y = fmaf(a1, wb[j].y, acc1.y);
            acc1.z = fmaf(a1, wb[j].z, acc1.z); acc1.w = fmaf(a1, wb[j].w, acc1.w);
            acc2.x = fmaf(a2, wb[j].x, acc2.x); acc2.y = fmaf(a2, wb[j].y, acc2.y);
            acc2.z = fmaf(a2, wb[j].z, acc2.z); acc2.w = fmaf(a2, wb[j].w, acc2.w);
            acc3.x = fmaf(a3, wb[j].x, acc3.x); acc3.y = fmaf(a3, wb[j].y, acc3.y);
            acc3.z = fmaf(a3, wb[j].z, acc3.z); acc3.w = fmaf(a3, wb[j].w, acc3.w);
        }
        #pragma unroll
        for (int j = 0; j < 4; ++j) wb[j] = wn[j];
    }

    // write partials [wave][row][col]
    *(float4*)&part[(wv * 4 + 0) * 256 + c0] = acc0;
    *(float4*)&part[(wv * 4 + 1) * 256 + c0] = acc1;
    *(float4*)&part[(wv * 4 + 2) * 256 + c0] = acc2;
    *(float4*)&part[(wv * 4 + 3) * 256 + c0] = acc3;
    __syncthreads();

    // reduce 4 k-partials; thread t = column; apply scale + exp2
    const int t = tid;
    float s[4];
    #pragma unroll
    for (int j = 0; j < 4; ++j) {
        const float v = part[(0 * 4 + j) * 256 + t] + part[(1 * 4 + j) * 256 + t]
                      + part[(2 * 4 + j) * 256 + t] + part[(3 * 4 + j) * 256 + t];
        s[j] = __builtin_amdgcn_exp2f(v * C2LOG2E);
    }

    if (isDe) {
        const int rr0 = (rb * 4) & 2047;   // rows within (B*T_de)
        #pragma unroll
        for (int j = 0; j < 4; ++j)
            att_de_exp[(rr0 + j) * 256 + t] = s[j];
    } else {
        const int b  = rb >> 6;
        const int er = (rb & 63) * 4;
        __syncthreads();                    // all part reads done
        #pragma unroll
        for (int j = 0; j < 4; ++j)
            part[j * 256 + t] = s[j];       // xs2[e_local][u]
        __syncthreads();
        const int ug = t >> 2;
        const int sl = t & 3;               // e_local
        const float4 v = *(const float4*)&part[sl * 256 + (ug << 2)];
        *(float4*)(att_enT4 + b * 65536 + ug * 1024 + (er + sl) * 4) = v;
    }
}

// ---------------------------------------------------------------------------
// Attention. grid 1024 x 256thr, TT=2, b = blk&7 (XCD-affine).
// Stage 1: lane = e; b128 loads of 4 packed Ea values per e (4-deep ring,
//   cur/nxt at FUNCTION scope — deeper rings spill, see R10 note);
//   sd/nu via uniform s_loads; E=Ea*sd; 4-way rcp combine; NO exp2 in loop.
// Stage 2: waves 0,1 softmax (min-trick). Stage 3: thread=d, alphas as
//   uniform b128 broadcasts, en coalesced dword, 8-deep.
// ---------------------------------------------------------------------------
__global__ __launch_bounds__(256, 4) void attn_kernel(
    const float* __restrict__ att_enT4,   // (B,64,T_en,4): Ea packed
    const float* __restrict__ att_de_exp, // (B,T_de,U): sd
    const float* __restrict__ en_seq,     // (B,T_en,D)
    const float* __restrict__ de_seq,     // (B,T_de,D)
    const float* __restrict__ nu,         // (U)
    float* __restrict__ out)              // (B,T_de,D)
{
    const int blk  = blockIdx.x;          // 0..1023
    const int b    = blk & 7;
    const int t0   = (blk >> 3) << 1;
    const int tid  = threadIdx.x;
    const int lane = tid & 63;
    const int wv   = __builtin_amdgcn_readfirstlane(tid >> 6);

    __shared__ float s_mu[2][256];
    __shared__ float s_al[2][256];

    const float* aw  = att_enT4 + b * 65536 + (((wv << 6) + lane) << 2);
    const float* sd0 = uptr(att_de_exp + (b * 256 + t0) * 256);
    const float* sd1 = uptr(att_de_exp + (b * 256 + t0) * 256 + 256);
    const float* nuu = uptr(nu);

    // ---- Stage 1: acc[t] = sum_u nu[u] / (Ea*sd + 1) ----
    float acc0 = 0.f, acc1 = 0.f;
    float4 cur[4], nxt[4];
    #pragma unroll
    for (int j = 0; j < 4; ++j)
        cur[j] = *(const float4*)(aw + j * 1024);

    for (int ugb = 0; ugb < 64; ugb += 4) {
        if (ugb < 60) {
            #pragma unroll
            for (int j = 0; j < 4; ++j)
                nxt[j] = *(const float4*)(aw + (ugb + 4 + j) * 1024);
        }
        #pragma unroll
        for (int j = 0; j < 4; ++j) {
            const int ub = (ugb + j) << 2;
            const float n0 = nuu[ub + 0], n1 = nuu[ub + 1];
            const float n2 = nuu[ub + 2], n3 = nuu[ub + 3];
            const float4 Ea = cur[j];
            {   // t = t0
                const float A0 = fmaf(Ea.x, sd0[ub + 0], 1.f);
                const float A1 = fmaf(Ea.y, sd0[ub + 1], 1.f);
                const float A2 = fmaf(Ea.z, sd0[ub + 2], 1.f);
                const float A3 = fmaf(Ea.w, sd0[ub + 3], 1.f);
                const float p01 = A0 * A1, p23 = A2 * A3;
                const float n01 = fmaf(n0, A1, n1 * A0);
                const float n23 = fmaf(n2, A3, n3 * A2);
                const float num = fmaf(n01, p23, n23 * p01);
                acc0 = fmaf(num, __builtin_amdgcn_rcpf(p01 * p23), acc0);
            }
            {   // t = t0+1
                const float A0 = fmaf(Ea.x, sd1[ub + 0], 1.f);
                const float A1 = fmaf(Ea.y, sd1[ub + 1], 1.f);
                const float A2 = fmaf(Ea.z, sd1[ub + 2], 1.f);
                const float A3 = fmaf(Ea.w, sd1[ub + 3], 1.f);
                const float p01 = A0 * A1, p23 = A2 * A3;
                const float n01 = fmaf(n0, A1, n1 * A0);
                const float n23 = fmaf(n2, A3, n3 * A2);
                const float num = fmaf(n01, p23, n23 * p01);
                acc1 = fmaf(num, __builtin_amdgcn_rcpf(p01 * p23), acc1);
            }
        }
        #pragma unroll
        for (int j = 0; j < 4; ++j) cur[j] = nxt[j];
    }
    const int eidx = (wv << 6) + lane;
    s_mu[0][eidx] = acc0;
    s_mu[1][eidx] = acc1;
    __syncthreads();

    // ---- Stage 2: softmax for t = wv (logits = const - 2*acc) ----
    if (wv < 2) {
        const float4 a = *(const float4*)&s_mu[wv][lane << 2];
        float mn = fminf(fminf(a.x, a.y), fminf(a.z, a.w));
        #pragma unroll
        for (int off = 32; off > 0; off >>= 1)
            mn = fminf(mn, __shfl_xor(mn, off, 64));
        const float p0 = __builtin_amdgcn_exp2f((mn - a.x) * C2LOG2E);
        const float p1 = __builtin_amdgcn_exp2f((mn - a.y) * C2LOG2E);
        const float p2 = __builtin_amdgcn_exp2f((mn - a.z) * C2LOG2E);
        const float p3 = __builtin_amdgcn_exp2f((mn - a.w) * C2LOG2E);
        float ssum = (p0 + p1) + (p2 + p3);
        #pragma unroll
        for (int off = 32; off > 0; off >>= 1)
            ssum += __shfl_xor(ssum, off, 64);
        const float inv = __builtin_amdgcn_rcpf(ssum);
        float4 al; al.x = p0 * inv; al.y = p1 * inv;
        al.z = p2 * inv; al.w = p3 * inv;
        *(float4*)&s_al[wv][lane << 2] = al;
    }
    __syncthreads();

    // ---- Stage 3: out[t][d] = de[t][d] + sum_e alpha[t][e]*en[e][d] ----
    const float* en_b = en_seq + b * 65536 + tid;
    float o0 = 0.f, o1 = 0.f;
    for (int e0 = 0; e0 < 256; e0 += 8) {
        float v[8];
        #pragma unroll
        for (int j = 0; j < 8; ++j) v[j] = en_b[(e0 + j) << 8];
        #pragma unroll
        for (int q = 0; q < 2; ++q) {
            const int eb = e0 + q * 4;
            const float4 A0 = *(const float4*)&s_al[0][eb];  // uniform bcast
            const float4 A1 = *(const float4*)&s_al[1][eb];
            o0 = fmaf(A0.x, v[q*4+0], o0); o1 = fmaf(A1.x, v[q*4+0], o1);
            o0 = fmaf(A0.y, v[q*4+1], o0); o1 = fmaf(A1.y, v[q*4+1], o1);
            o0 = fmaf(A0.z, v[q*4+2], o0); o1 = fmaf(A1.z, v[q*4+2], o1);
            o0 = fmaf(A0.w, v[q*4+3], o0); o1 = fmaf(A1.w, v[q*4+3], o1);
        }
    }
    const int base = (b * 256 + t0) * 256 + tid;
    out[base]       = de_seq[base]       + o0;
    out[base + 256] = de_seq[base + 256] + o1;
}

extern "C" void kernel_launch(void* const* d_in, const int* in_sizes, int n_in,
                              void* d_out, int out_size, void* d_ws, size_t ws_size,
                              hipStream_t stream) {
    const float* en_seq = (const float*)d_in[0];
    const float* de_seq = (const float*)d_in[1];
    const float* w_en   = (const float*)d_in[2];
    const float* w_de   = (const float*)d_in[3];
    const float* nu     = (const float*)d_in[4];
    float* out = (float*)d_out;

    float* att_enT4   = (float*)d_ws;                // 2MB: Ea, packed
    float* att_de_exp = att_enT4 + 8 * 256 * 256;    // 2MB: sd

    gemm2<<<1024, 256, 0, stream>>>(en_seq, de_seq, w_en, w_de,
                                    att_enT4, att_de_exp);
    attn_kernel<<<1024, 256, 0, stream>>>(att_enT4, att_de_exp, en_seq,
                                          de_seq, nu, out);
}